// Round 6
// baseline (180.859 us; speedup 1.0000x reference)
//
#include <hip/hip_runtime.h>
#include <hip/hip_bf16.h>

#define BATCH 16
#define NCAND 25200
#define NCLS 80
#define PREDC 85
#define KTOP 1000
#define MAXDET 300
#define CAP 2048
#define NBINS 1024
#define TILE_ROWS 128
#define CONF 0.45f
#define HSCALE ((float)NBINS / (1.0f - 0.45f))
#define CNT_STRIDE 16   // ints; 64B between per-image counters

typedef unsigned long long ull;

// ---------------- K0: zero/init workspace ----------------
__global__ __launch_bounds__(256) void k_init(int* __restrict__ hist,
                                              ull* __restrict__ keys,
                                              int* __restrict__ cnt) {
    int t = blockIdx.x * 256 + threadIdx.x;          // 128 blocks -> 32768 threads
    keys[t] = ~0ULL;                                 // 16*2048 = 32768
    if (t < BATCH * NBINS) hist[t] = 0;              // 16384
    if (t < BATCH * CNT_STRIDE) cnt[t] = 0;
}

// ---------------- K1: per-candidate score + global histogram ----------------
__global__ __launch_bounds__(256) void k_score(const float* __restrict__ pred,
                                               float* __restrict__ score,
                                               int* __restrict__ hist) {
    __shared__ float lds[TILE_ROWS * PREDC];   // 43,520 B
    int tile = blockIdx.x;
    int tid = threadIdx.x;
    size_t base = (size_t)tile * (TILE_ROWS * PREDC);
    const float4* src4 = (const float4*)(pred + base);
    float4* l4 = (float4*)lds;
    const int NV4 = TILE_ROWS * PREDC / 4;  // 2720
    for (int k = tid; k < NV4; k += 256) l4[k] = src4[k];
    __syncthreads();
    if (tid < TILE_ROWS) {
        const float* row = lds + tid * PREDC;
        float obj = row[4];
        float best = -1.0f;
        #pragma unroll 8
        for (int c = 0; c < NCLS; ++c) {
            float v = row[5 + c] * obj;
            if (v > best) best = v;
        }
        bool valid = (obj > CONF) && (best > CONF);
        float s = valid ? best : -1.0f;
        int grow = tile * TILE_ROWS + tid;
        score[grow] = s;
        if (s > CONF) {
            int b = grow / NCAND;
            int bin = (int)((s - CONF) * HSCALE);
            bin = bin < 0 ? 0 : (bin > NBINS - 1 ? NBINS - 1 : bin);
            atomicAdd(&hist[b * NBINS + bin], 1);
        }
    }
}

// ---------------- K2: per-image threshold bin via suffix scan ----------------
__global__ __launch_bounds__(256) void k_findT(const int* __restrict__ hist,
                                               int* __restrict__ Tarr) {
    int b = blockIdx.x, tid = threadIdx.x;
    __shared__ int h[NBINS];
    __shared__ int s_T;
    if (tid == 0) s_T = 0;
    #pragma unroll
    for (int k = 0; k < 4; ++k) h[tid + k * 256] = hist[b * NBINS + tid + k * 256];
    __syncthreads();
    for (int off = 1; off < NBINS; off <<= 1) {
        int tmp[4];
        #pragma unroll
        for (int k = 0; k < 4; ++k) {
            int idx = tid + k * 256;
            tmp[k] = (idx + off < NBINS) ? h[idx + off] : 0;
        }
        __syncthreads();
        #pragma unroll
        for (int k = 0; k < 4; ++k) h[tid + k * 256] += tmp[k];
        __syncthreads();
    }
    #pragma unroll
    for (int k = 0; k < 4; ++k) {
        int idx = tid + k * 256;
        int S = h[idx];
        int Sn = (idx + 1 < NBINS) ? h[idx + 1] : 0;
        if (S >= KTOP && Sn < KTOP) s_T = idx;   // unique (suffix monotone)
    }
    __syncthreads();
    if (tid == 0) Tarr[b] = s_T;
}

// ---------------- K3: gather survivors, one atomic per block ----------------
__global__ __launch_bounds__(256) void k_gather(const float* __restrict__ score,
                                                const int* __restrict__ Tarr,
                                                ull* __restrict__ keys,
                                                int* __restrict__ cnt) {
    int b = blockIdx.y;
    int n = blockIdx.x * 256 + threadIdx.x;
    int tid = threadIdx.x;
    __shared__ int wbase[4];
    __shared__ int sT;
    if (tid == 0) sT = Tarr[b];
    __syncthreads();
    bool want = false;
    float s = 0.0f;
    if (n < NCAND) {
        s = score[b * NCAND + n];
        if (s > CONF) {
            int bin = (int)((s - CONF) * HSCALE);
            bin = bin < 0 ? 0 : (bin > NBINS - 1 ? NBINS - 1 : bin);
            want = (bin >= sT);
        }
    }
    ull m = __ballot(want);
    int lane = tid & 63, widx = tid >> 6;
    if (lane == 0) wbase[widx] = __popcll(m);
    __syncthreads();
    if (tid == 0) {
        int t0 = wbase[0], t1 = wbase[1], t2 = wbase[2], t3 = wbase[3];
        int tot = t0 + t1 + t2 + t3;
        int b0 = tot ? atomicAdd(&cnt[b * CNT_STRIDE], tot) : 0;
        wbase[0] = b0; wbase[1] = b0 + t0; wbase[2] = b0 + t0 + t1; wbase[3] = b0 + t0 + t1 + t2;
    }
    __syncthreads();
    if (want) {
        int pos = wbase[widx] + __popcll(m & ((1ULL << lane) - 1ULL));
        if (pos < CAP) {
            unsigned int sb = __float_as_uint(s);
            keys[b * CAP + pos] = ((ull)(~sb) << 32) | (unsigned)n;
        }
    }
}

// ---------------- K4: per-image bitonic sort (P=1024 or 2048) + emit top-K ----
__global__ __launch_bounds__(1024) void k_sort(const float* __restrict__ pred,
                                               const ull* __restrict__ keys,
                                               const int* __restrict__ cnt,
                                               int* __restrict__ topidx,
                                               float* __restrict__ topsc,
                                               int* __restrict__ topcls,
                                               float* __restrict__ boxes) {
    int b = blockIdx.x, tid = threadIdx.x;
    __shared__ ull sbuf[CAP];
    __shared__ int s_C2;
    if (tid == 0) {
        int c = cnt[b * CNT_STRIDE];
        s_C2 = c > CAP ? CAP : c;
    }
    __syncthreads();
    int C2 = s_C2;
    unsigned P = (C2 <= 1024) ? 1024u : 2048u;
    sbuf[tid] = keys[b * CAP + tid];
    if (P > 1024) sbuf[tid + 1024] = keys[b * CAP + tid + 1024];
    __syncthreads();
    for (unsigned k = 2; k <= P; k <<= 1) {
        for (unsigned j = k >> 1; j > 0; j >>= 1) {
            for (unsigned t = tid; t < P; t += 1024) {
                unsigned ixj = t ^ j;
                if (ixj > t) {
                    ull a = sbuf[t], bb = sbuf[ixj];
                    if ((a > bb) == ((t & k) == 0)) { sbuf[t] = bb; sbuf[ixj] = a; }
                }
            }
            __syncthreads();
        }
    }
    if (tid < KTOP) {
        int o = b * KTOP + tid;
        if (tid < C2) {
            ull key = sbuf[tid];
            int n = (int)(key & 0xFFFFFFFFULL);
            float s = __uint_as_float(~(unsigned int)(key >> 32));
            const float* row = pred + ((size_t)b * NCAND + n) * PREDC;
            float cx = row[0], cy = row[1], w = row[2], h = row[3];
            float obj = row[4];
            float best = -1.0f; int bj = 0;
            for (int c = 0; c < NCLS; ++c) {
                float v = row[5 + c] * obj;
                if (v > best) { best = v; bj = c; }
            }
            topidx[o] = n; topsc[o] = s; topcls[o] = bj;
            ((float4*)boxes)[o] = make_float4(cx - w * 0.5f, cy - h * 0.5f,
                                              cx + w * 0.5f, cy + h * 0.5f);
        } else {
            topidx[o] = 0; topsc[o] = -1.0f; topcls[o] = 0;
            ((float4*)boxes)[o] = make_float4(0.f, 0.f, 0.f, 0.f);
        }
    }
}

// ---------------- K5: IoU bitmask (j>i, iou>thr) ----------------
__global__ __launch_bounds__(256) void k_iou(const float* __restrict__ boxes,
                                             ull* __restrict__ M) {
    #pragma clang fp contract(off)
    int g = blockIdx.x * 256 + threadIdx.x;   // 16*1000*16 = 256000
    int w = g & 15;
    int bi = g >> 4;                          // 0..15999
    int i = bi % KTOP;
    int b = bi / KTOP;
    int j0 = w * 64;
    if (j0 + 63 <= i) {                       // whole block strictly j<=i -> zero
        M[(size_t)bi * 16 + w] = 0ULL;
        return;
    }
    const float4* bx = (const float4*)boxes + (size_t)b * KTOP;
    float4 A = bx[i];
    float areaA = (A.z - A.x) * (A.w - A.y);
    ull word = 0;
    int jend = j0 + 64; if (jend > KTOP) jend = KTOP;
    #pragma unroll 4
    for (int j = j0; j < jend; ++j) {
        float4 Bb = bx[j];
        float areaB = (Bb.z - Bb.x) * (Bb.w - Bb.y);
        float lx = fmaxf(A.x, Bb.x), ly = fmaxf(A.y, Bb.y);
        float rx = fminf(A.z, Bb.z), ry = fminf(A.w, Bb.w);
        float ww = rx - lx; ww = ww > 0.f ? ww : 0.f;
        float hh = ry - ly; hh = hh > 0.f ? hh : 0.f;
        float inter = ww * hh;
        float denom = ((areaA + areaB) - inter) + 1e-9f;
        float iou = inter / denom;
        if (j > i && iou > 0.45f) word |= 1ULL << (j - j0);
    }
    M[(size_t)bi * 16 + w] = word;
}

// ---------------- K6: block-NMS (scalar 64-step resolve) + top-300 outputs ------
__global__ __launch_bounds__(256) void k_nms_out(const ull* __restrict__ M,
                                                 const int* __restrict__ cnt,
                                                 const float* __restrict__ logits,
                                                 const int* __restrict__ topidx,
                                                 const float* __restrict__ topsc,
                                                 const int* __restrict__ topcls,
                                                 const float* __restrict__ boxes,
                                                 float* __restrict__ out) {
    __shared__ ull s_keep[16];
    __shared__ int kept_r[MAXDET];
    __shared__ int kept_n[MAXDET];
    __shared__ int s_kc;
    int b = blockIdx.x, tid = threadIdx.x;
    int kc0 = cnt[b * CNT_STRIDE]; if (kc0 > KTOP) kc0 = KTOP;
    const ull* Mb = M + (size_t)b * KTOP * 16;
    if (tid < 64) {
        int l = tid, w = l & 15, q = l >> 4;
        // supp word w (4 replicas across lanes); init: rows >= kc0 suppressed
        ull supp;
        {
            int lo = w * 64;
            if (kc0 <= lo) supp = ~0ULL;
            else if (kc0 >= lo + 64) supp = 0ULL;
            else supp = (~0ULL) << (kc0 - lo);
        }
        for (int rb = 0; rb < 16; ++rb) {
            int base = rb * 64;
            // diag row word: lane l -> M[base+l][rb]
            int di = base + l; di = di < KTOP ? di : KTOP - 1;
            ull drow = Mb[(size_t)di * 16 + rb];
            // contribution rows: lane (w,q) -> rows base+q+4k, word w (coalesced)
            ull crow[16];
            #pragma unroll
            for (int k = 0; k < 16; ++k) {
                int g = base + q + 4 * k; g = g < KTOP ? g : KTOP - 1;
                crow[k] = Mb[(size_t)g * 16 + w];
            }
            // extract merged supp word rb -> wave-uniform scalar
            int slo = (int)(supp & 0xffffffffULL);
            int shi = (int)(supp >> 32);
            unsigned rlo = (unsigned)__builtin_amdgcn_readlane(slo, rb)
                         | (unsigned)__builtin_amdgcn_readlane(slo, rb + 16)
                         | (unsigned)__builtin_amdgcn_readlane(slo, rb + 32)
                         | (unsigned)__builtin_amdgcn_readlane(slo, rb + 48);
            unsigned rhi = (unsigned)__builtin_amdgcn_readlane(shi, rb)
                         | (unsigned)__builtin_amdgcn_readlane(shi, rb + 16)
                         | (unsigned)__builtin_amdgcn_readlane(shi, rb + 32)
                         | (unsigned)__builtin_amdgcn_readlane(shi, rb + 48);
            ull removed = ((ull)rhi << 32) | rlo;
            // 64-step serial resolve on wave-uniform scalars; readlanes are
            // independent of the chain (drow is fixed), so they pipeline.
            int dlo_v = (int)(drow & 0xffffffffULL);
            int dhi_v = (int)(drow >> 32);
            #pragma unroll
            for (int s = 0; s < 64; ++s) {
                unsigned dl = (unsigned)__builtin_amdgcn_readlane(dlo_v, s);
                unsigned dh = (unsigned)__builtin_amdgcn_readlane(dhi_v, s);
                ull d64 = ((ull)dh << 32) | dl;
                if (!((removed >> s) & 1ULL)) removed |= d64;
            }
            // dense parallel apply: OR alive rows' words into supp partials
            ull acc = 0;
            #pragma unroll
            for (int k = 0; k < 16; ++k) {
                int r = q + 4 * k;
                if (!((removed >> r) & 1ULL)) acc |= crow[k];
            }
            supp |= acc;
        }
        // merge the 4 replicas per word
        supp |= __shfl_xor(supp, 16);
        supp |= __shfl_xor(supp, 32);
        if (l < 16) s_keep[l] = ~supp;
    }
    __syncthreads();
    // ---- output phase (all 256 threads) ----
    if (tid < 16) {
        int pre = 0;
        for (int u = 0; u < tid; ++u) pre += __popcll(s_keep[u]);
        ull wv = s_keep[tid];
        int rank = pre;
        while (wv) {
            int bit = __builtin_ctzll(wv);
            if (rank < MAXDET) kept_r[rank] = tid * 64 + bit;
            rank++;
            wv &= wv - 1;
        }
        if (tid == 15) s_kc = rank < MAXDET ? rank : MAXDET;
    }
    __syncthreads();
    int kc = s_kc;
    for (int s = tid; s < MAXDET; s += 256)
        if (s < kc) kept_n[s] = topidx[b * KTOP + kept_r[s]];
    __syncthreads();
    float* det = out;                                        // [16][300][6]
    float* mask_o = out + BATCH * MAXDET * 6;                // [16][300]
    float* lgo = out + BATCH * MAXDET * 6 + BATCH * MAXDET;  // [16][300][80]
    for (int idx = tid; idx < MAXDET * 6; idx += 256) {
        int s = idx / 6, col = idx % 6;
        float v = 0.f;
        if (s < kc) {
            int o = b * KTOP + kept_r[s];
            if (col < 4) v = boxes[o * 4 + col];
            else if (col == 4) v = topsc[o];
            else v = (float)topcls[o];
        }
        det[b * MAXDET * 6 + idx] = v;
    }
    for (int s = tid; s < MAXDET; s += 256)
        mask_o[b * MAXDET + s] = (s < kc) ? 1.0f : 0.0f;
    for (int idx = tid; idx < MAXDET * NCLS; idx += 256) {
        int s = idx / NCLS, c = idx % NCLS;
        float v = 0.f;
        if (s < kc) v = logits[((size_t)b * NCAND + kept_n[s]) * NCLS + c];
        lgo[b * MAXDET * NCLS + idx] = v;
    }
}

extern "C" void kernel_launch(void* const* d_in, const int* in_sizes, int n_in,
                              void* d_out, int out_size, void* d_ws, size_t ws_size,
                              hipStream_t stream) {
    (void)in_sizes; (void)n_in; (void)out_size; (void)ws_size;
    const float* pred = (const float*)d_in[0];
    const float* logits = (const float*)d_in[1];
    float* out = (float*)d_out;
    char* ws = (char*)d_ws;

    // workspace layout (bytes). Region A is time-shared:
    //   score/hist/Tarr live K0..K3; M (2,048,000) overlays them, live K5..K6.
    float* score  = (float*)(ws + 0);                    // 1,612,800
    int*   hist   = (int*)(ws + 1612800);                // 65,536
    int*   Tarr   = (int*)(ws + 1678336);                // 64
    ull*   M      = (ull*)(ws + 0);                      // 2,048,000 (overlay)
    ull*   keys   = (ull*)(ws + 2048000);                // 262,144
    int*   cnt    = (int*)(ws + 2310144);                // 1,024 (16 imgs x 64B)
    int*   topidx = (int*)(ws + 2311168);                // 64,000
    float* topsc  = (float*)(ws + 2375168);              // 64,000
    int*   topcls = (int*)(ws + 2439168);                // 64,000
    float* boxes  = (float*)(ws + 2503168);              // 256,000 (16B aligned)

    const int nrows = BATCH * NCAND;                     // 403200
    k_init<<<128, 256, 0, stream>>>(hist, keys, cnt);
    k_score<<<nrows / TILE_ROWS, 256, 0, stream>>>(pred, score, hist);
    k_findT<<<BATCH, 256, 0, stream>>>(hist, Tarr);
    k_gather<<<dim3((NCAND + 255) / 256, BATCH), 256, 0, stream>>>(score, Tarr, keys, cnt);
    k_sort<<<BATCH, 1024, 0, stream>>>(pred, keys, cnt, topidx, topsc, topcls, boxes);
    k_iou<<<(BATCH * KTOP * 16) / 256, 256, 0, stream>>>(boxes, M);
    k_nms_out<<<BATCH, 256, 0, stream>>>(M, cnt, logits, topidx, topsc, topcls, boxes, out);
}

// Round 7
// 154.621 us; speedup vs baseline: 1.1697x; 1.1697x over previous
//
#include <hip/hip_runtime.h>
#include <hip/hip_bf16.h>

#define BATCH 16
#define NCAND 25200
#define NCLS 80
#define PREDC 85
#define KTOP 1000
#define MAXDET 300
#define CAP 2048
#define NBINS 1024
#define TILE_ROWS 128
#define CONF 0.45f
#define HSCALE ((float)NBINS / (1.0f - 0.45f))
#define CNT_STRIDE 16   // ints; 64B between per-image counters
#define OSLICE 40

typedef unsigned long long ull;

// ---------------- K0: zero/init workspace ----------------
__global__ __launch_bounds__(256) void k_init(int* __restrict__ hist,
                                              ull* __restrict__ keys,
                                              int* __restrict__ cnt) {
    int t = blockIdx.x * 256 + threadIdx.x;          // 128 blocks -> 32768 threads
    keys[t] = ~0ULL;                                 // 16*2048 = 32768
    if (t < BATCH * NBINS) hist[t] = 0;              // 16384
    if (t < BATCH * CNT_STRIDE) cnt[t] = 0;
}

// ---------------- K1: per-candidate score + global histogram ----------------
__global__ __launch_bounds__(256) void k_score(const float* __restrict__ pred,
                                               float* __restrict__ score,
                                               int* __restrict__ hist) {
    __shared__ float lds[TILE_ROWS * PREDC];   // 43,520 B
    int tile = blockIdx.x;
    int tid = threadIdx.x;
    size_t base = (size_t)tile * (TILE_ROWS * PREDC);
    const float4* src4 = (const float4*)(pred + base);
    float4* l4 = (float4*)lds;
    const int NV4 = TILE_ROWS * PREDC / 4;  // 2720
    for (int k = tid; k < NV4; k += 256) l4[k] = src4[k];
    __syncthreads();
    if (tid < TILE_ROWS) {
        const float* row = lds + tid * PREDC;
        float obj = row[4];
        float best = -1.0f;
        #pragma unroll 8
        for (int c = 0; c < NCLS; ++c) {
            float v = row[5 + c] * obj;
            if (v > best) best = v;
        }
        bool valid = (obj > CONF) && (best > CONF);
        float s = valid ? best : -1.0f;
        int grow = tile * TILE_ROWS + tid;
        score[grow] = s;
        if (s > CONF) {
            int b = grow / NCAND;
            int bin = (int)((s - CONF) * HSCALE);
            bin = bin < 0 ? 0 : (bin > NBINS - 1 ? NBINS - 1 : bin);
            atomicAdd(&hist[b * NBINS + bin], 1);
        }
    }
}

// ---------------- K2: per-image threshold bin via suffix scan ----------------
__global__ __launch_bounds__(256) void k_findT(const int* __restrict__ hist,
                                               int* __restrict__ Tarr) {
    int b = blockIdx.x, tid = threadIdx.x;
    __shared__ int h[NBINS];
    __shared__ int s_T;
    if (tid == 0) s_T = 0;
    #pragma unroll
    for (int k = 0; k < 4; ++k) h[tid + k * 256] = hist[b * NBINS + tid + k * 256];
    __syncthreads();
    for (int off = 1; off < NBINS; off <<= 1) {
        int tmp[4];
        #pragma unroll
        for (int k = 0; k < 4; ++k) {
            int idx = tid + k * 256;
            tmp[k] = (idx + off < NBINS) ? h[idx + off] : 0;
        }
        __syncthreads();
        #pragma unroll
        for (int k = 0; k < 4; ++k) h[tid + k * 256] += tmp[k];
        __syncthreads();
    }
    #pragma unroll
    for (int k = 0; k < 4; ++k) {
        int idx = tid + k * 256;
        int S = h[idx];
        int Sn = (idx + 1 < NBINS) ? h[idx + 1] : 0;
        if (S >= KTOP && Sn < KTOP) s_T = idx;   // unique (suffix monotone)
    }
    __syncthreads();
    if (tid == 0) Tarr[b] = s_T;
}

// ---------------- K3: gather survivors, one atomic per block ----------------
__global__ __launch_bounds__(256) void k_gather(const float* __restrict__ score,
                                                const int* __restrict__ Tarr,
                                                ull* __restrict__ keys,
                                                int* __restrict__ cnt) {
    int b = blockIdx.y;
    int n = blockIdx.x * 256 + threadIdx.x;
    int tid = threadIdx.x;
    __shared__ int wbase[4];
    __shared__ int sT;
    if (tid == 0) sT = Tarr[b];
    __syncthreads();
    bool want = false;
    float s = 0.0f;
    if (n < NCAND) {
        s = score[b * NCAND + n];
        if (s > CONF) {
            int bin = (int)((s - CONF) * HSCALE);
            bin = bin < 0 ? 0 : (bin > NBINS - 1 ? NBINS - 1 : bin);
            want = (bin >= sT);
        }
    }
    ull m = __ballot(want);
    int lane = tid & 63, widx = tid >> 6;
    if (lane == 0) wbase[widx] = __popcll(m);
    __syncthreads();
    if (tid == 0) {
        int t0 = wbase[0], t1 = wbase[1], t2 = wbase[2], t3 = wbase[3];
        int tot = t0 + t1 + t2 + t3;
        int b0 = tot ? atomicAdd(&cnt[b * CNT_STRIDE], tot) : 0;
        wbase[0] = b0; wbase[1] = b0 + t0; wbase[2] = b0 + t0 + t1; wbase[3] = b0 + t0 + t1 + t2;
    }
    __syncthreads();
    if (want) {
        int pos = wbase[widx] + __popcll(m & ((1ULL << lane) - 1ULL));
        if (pos < CAP) {
            unsigned int sb = __float_as_uint(s);
            keys[b * CAP + pos] = ((ull)(~sb) << 32) | (unsigned)n;
        }
    }
}

// ---------------- K4: per-image bitonic sort (P=1024 or 2048) + emit top-K ----
__global__ __launch_bounds__(1024) void k_sort(const float* __restrict__ pred,
                                               const ull* __restrict__ keys,
                                               const int* __restrict__ cnt,
                                               int* __restrict__ topidx,
                                               float* __restrict__ topsc,
                                               int* __restrict__ topcls,
                                               float* __restrict__ boxes) {
    int b = blockIdx.x, tid = threadIdx.x;
    __shared__ ull sbuf[CAP];
    __shared__ int s_C2;
    if (tid == 0) {
        int c = cnt[b * CNT_STRIDE];
        s_C2 = c > CAP ? CAP : c;
    }
    __syncthreads();
    int C2 = s_C2;
    unsigned P = (C2 <= 1024) ? 1024u : 2048u;
    sbuf[tid] = keys[b * CAP + tid];
    if (P > 1024) sbuf[tid + 1024] = keys[b * CAP + tid + 1024];
    __syncthreads();
    for (unsigned k = 2; k <= P; k <<= 1) {
        for (unsigned j = k >> 1; j > 0; j >>= 1) {
            for (unsigned t = tid; t < P; t += 1024) {
                unsigned ixj = t ^ j;
                if (ixj > t) {
                    ull a = sbuf[t], bb = sbuf[ixj];
                    if ((a > bb) == ((t & k) == 0)) { sbuf[t] = bb; sbuf[ixj] = a; }
                }
            }
            __syncthreads();
        }
    }
    if (tid < KTOP) {
        int o = b * KTOP + tid;
        if (tid < C2) {
            ull key = sbuf[tid];
            int n = (int)(key & 0xFFFFFFFFULL);
            float s = __uint_as_float(~(unsigned int)(key >> 32));
            const float* row = pred + ((size_t)b * NCAND + n) * PREDC;
            float cx = row[0], cy = row[1], w = row[2], h = row[3];
            float obj = row[4];
            float best = -1.0f; int bj = 0;
            for (int c = 0; c < NCLS; ++c) {
                float v = row[5 + c] * obj;
                if (v > best) { best = v; bj = c; }
            }
            topidx[o] = n; topsc[o] = s; topcls[o] = bj;
            ((float4*)boxes)[o] = make_float4(cx - w * 0.5f, cy - h * 0.5f,
                                              cx + w * 0.5f, cy + h * 0.5f);
        } else {
            topidx[o] = 0; topsc[o] = -1.0f; topcls[o] = 0;
            ((float4*)boxes)[o] = make_float4(0.f, 0.f, 0.f, 0.f);
        }
    }
}

// ---------------- K5: IoU bitmask (j>i, iou>thr) ----------------
__global__ __launch_bounds__(256) void k_iou(const float* __restrict__ boxes,
                                             ull* __restrict__ M) {
    #pragma clang fp contract(off)
    int g = blockIdx.x * 256 + threadIdx.x;   // 16*1000*16 = 256000
    int w = g & 15;
    int bi = g >> 4;                          // 0..15999
    int i = bi % KTOP;
    int b = bi / KTOP;
    int j0 = w * 64;
    if (j0 + 63 <= i) {                       // whole block strictly j<=i -> zero
        M[(size_t)bi * 16 + w] = 0ULL;
        return;
    }
    const float4* bx = (const float4*)boxes + (size_t)b * KTOP;
    float4 A = bx[i];
    float areaA = (A.z - A.x) * (A.w - A.y);
    ull word = 0;
    int jend = j0 + 64; if (jend > KTOP) jend = KTOP;
    #pragma unroll 4
    for (int j = j0; j < jend; ++j) {
        float4 Bb = bx[j];
        float areaB = (Bb.z - Bb.x) * (Bb.w - Bb.y);
        float lx = fmaxf(A.x, Bb.x), ly = fmaxf(A.y, Bb.y);
        float rx = fminf(A.z, Bb.z), ry = fminf(A.w, Bb.w);
        float ww = rx - lx; ww = ww > 0.f ? ww : 0.f;
        float hh = ry - ly; hh = hh > 0.f ? hh : 0.f;
        float inter = ww * hh;
        float denom = ((areaA + areaB) - inter) + 1e-9f;
        float iou = inter / denom;
        if (j > i && iou > 0.45f) word |= 1ULL << (j - j0);
    }
    M[(size_t)bi * 16 + w] = word;
}

// ---------------- K6: block-NMS; staging waves + wave0 scalar resolve from LDS ----
__global__ __launch_bounds__(1024) void k_nms(const ull* __restrict__ M,
                                              const int* __restrict__ cnt,
                                              const int* __restrict__ topidx,
                                              int* __restrict__ keptr,
                                              int* __restrict__ keptn,
                                              int* __restrict__ kcarr) {
    __shared__ ull buf[2][64 * 17];   // stride-17 pad: <=4-way bank conflict
    __shared__ ull s_keep[16];
    __shared__ int s_keptr[MAXDET];
    __shared__ int s_kc;
    int b = blockIdx.x, tid = threadIdx.x;
    int kc0 = cnt[b * CNT_STRIDE]; if (kc0 > KTOP) kc0 = KTOP;
    const ull* Mb = M + (size_t)b * KTOP * 16;
    // stage block 0 (all 1024 threads, coalesced)
    buf[0][(tid >> 4) * 17 + (tid & 15)] = Mb[tid];
    __syncthreads();
    ull supp;
    {
        int w = tid & 15, lo = w * 64;
        if (kc0 <= lo) supp = ~0ULL;
        else if (kc0 >= lo + 64) supp = 0ULL;
        else supp = (~0ULL) << (kc0 - lo);
    }
    for (int rb = 0; rb < 16; ++rb) {
        int cur = rb & 1, nxt = cur ^ 1;
        if (tid >= 64) {
            if (rb < 15) {
                // 960 threads stage the next 1024-word block
                for (int u = tid - 64; u < 1024; u += 960) {
                    int idx = (rb + 1) * 1024 + u;
                    int g = idx < 16000 ? idx : 15999;   // tail garbage is masked by 'removed'
                    buf[nxt][(u >> 4) * 17 + (u & 15)] = Mb[g];
                }
            }
        } else {
            int l = tid, w = l & 15, q = l >> 4;
            const ull* B = buf[cur];
            ull drow = B[l * 17 + rb];
            ull crow[16];
            #pragma unroll
            for (int k = 0; k < 16; ++k) crow[k] = B[(q + 4 * k) * 17 + w];
            // merged supp word rb -> wave-uniform scalar
            int slo = (int)(supp & 0xffffffffULL);
            int shi = (int)(supp >> 32);
            unsigned rlo = (unsigned)__builtin_amdgcn_readlane(slo, rb)
                         | (unsigned)__builtin_amdgcn_readlane(slo, rb + 16)
                         | (unsigned)__builtin_amdgcn_readlane(slo, rb + 32)
                         | (unsigned)__builtin_amdgcn_readlane(slo, rb + 48);
            unsigned rhi = (unsigned)__builtin_amdgcn_readlane(shi, rb)
                         | (unsigned)__builtin_amdgcn_readlane(shi, rb + 16)
                         | (unsigned)__builtin_amdgcn_readlane(shi, rb + 32)
                         | (unsigned)__builtin_amdgcn_readlane(shi, rb + 48);
            ull removed = ((ull)rhi << 32) | rlo;
            int dlo_v = (int)(drow & 0xffffffffULL);
            int dhi_v = (int)(drow >> 32);
            // 64-step serial resolve on wave-uniform scalars (SALU chain);
            // readlanes feed from fixed drow -> pipeline independent of chain
            #pragma unroll
            for (int s = 0; s < 64; ++s) {
                unsigned dl = (unsigned)__builtin_amdgcn_readlane(dlo_v, s);
                unsigned dh = (unsigned)__builtin_amdgcn_readlane(dhi_v, s);
                ull d64 = ((ull)dh << 32) | dl;
                if (!((removed >> s) & 1ULL)) removed |= d64;
            }
            // dense parallel apply
            ull acc = 0;
            #pragma unroll
            for (int k = 0; k < 16; ++k) {
                int r = q + 4 * k;
                if (!((removed >> r) & 1ULL)) acc |= crow[k];
            }
            supp |= acc;
        }
        __syncthreads();
    }
    if (tid < 64) {
        supp |= __shfl_xor(supp, 16);
        supp |= __shfl_xor(supp, 32);
        if (tid < 16) s_keep[tid] = ~supp;
    }
    __syncthreads();
    if (tid < 16) {
        int pre = 0;
        for (int u = 0; u < tid; ++u) pre += __popcll(s_keep[u]);
        ull wv = s_keep[tid];
        int rank = pre;
        while (wv) {
            int bit = __builtin_ctzll(wv);
            if (rank < MAXDET) s_keptr[rank] = tid * 64 + bit;
            rank++;
            wv &= wv - 1;
        }
        if (tid == 15) s_kc = rank < MAXDET ? rank : MAXDET;
    }
    __syncthreads();
    int kc = s_kc;
    if (tid < MAXDET && tid < kc) {
        int r = s_keptr[tid];
        keptr[b * MAXDET + tid] = r;
        keptn[b * MAXDET + tid] = topidx[b * KTOP + r];
    }
    if (tid == 0) kcarr[b * CNT_STRIDE] = kc;
}

// ---------------- K7: outputs, 128 blocks for scattered-gather concurrency -------
__global__ __launch_bounds__(256) void k_out(const float* __restrict__ logits,
                                             const float* __restrict__ boxes,
                                             const float* __restrict__ topsc,
                                             const int* __restrict__ topcls,
                                             const int* __restrict__ keptr,
                                             const int* __restrict__ keptn,
                                             const int* __restrict__ kcarr,
                                             float* __restrict__ out) {
    int b = blockIdx.x, c = blockIdx.y, tid = threadIdx.x;
    int kc = kcarr[b * CNT_STRIDE];
    int s0 = c * OSLICE;
    float* det = out;                                        // [16][300][6]
    float* mask_o = out + BATCH * MAXDET * 6;                // [16][300]
    float* lgo = out + BATCH * MAXDET * 6 + BATCH * MAXDET;  // [16][300][80]
    for (int idx = tid; idx < OSLICE * 6; idx += 256) {
        int s = s0 + idx / 6, col = idx % 6;
        if (s < MAXDET) {
            float v = 0.f;
            if (s < kc) {
                int o = b * KTOP + keptr[b * MAXDET + s];
                if (col < 4) v = boxes[o * 4 + col];
                else if (col == 4) v = topsc[o];
                else v = (float)topcls[o];
            }
            det[b * MAXDET * 6 + s * 6 + col] = v;
        }
    }
    for (int idx = tid; idx < OSLICE; idx += 256) {
        int s = s0 + idx;
        if (s < MAXDET) mask_o[b * MAXDET + s] = (s < kc) ? 1.0f : 0.0f;
    }
    for (int idx = tid; idx < OSLICE * NCLS; idx += 256) {
        int s = s0 + idx / NCLS, cc = idx % NCLS;
        if (s < MAXDET) {
            float v = 0.f;
            if (s < kc) v = logits[((size_t)b * NCAND + keptn[b * MAXDET + s]) * NCLS + cc];
            lgo[b * MAXDET * NCLS + s * NCLS + cc] = v;
        }
    }
}

extern "C" void kernel_launch(void* const* d_in, const int* in_sizes, int n_in,
                              void* d_out, int out_size, void* d_ws, size_t ws_size,
                              hipStream_t stream) {
    (void)in_sizes; (void)n_in; (void)out_size; (void)ws_size;
    const float* pred = (const float*)d_in[0];
    const float* logits = (const float*)d_in[1];
    float* out = (float*)d_out;
    char* ws = (char*)d_ws;

    // workspace layout (bytes). Region A is time-shared:
    //   score/hist/Tarr live K0..K3; M (2,048,000) overlays them, live K5..K6.
    float* score  = (float*)(ws + 0);                    // 1,612,800
    int*   hist   = (int*)(ws + 1612800);                // 65,536
    int*   Tarr   = (int*)(ws + 1678336);                // 64
    ull*   M      = (ull*)(ws + 0);                      // 2,048,000 (overlay)
    ull*   keys   = (ull*)(ws + 2048000);                // 262,144
    int*   cnt    = (int*)(ws + 2310144);                // 1,024 (16 imgs x 64B)
    int*   topidx = (int*)(ws + 2311168);                // 64,000
    float* topsc  = (float*)(ws + 2375168);              // 64,000
    int*   topcls = (int*)(ws + 2439168);                // 64,000
    float* boxes  = (float*)(ws + 2503168);              // 256,000 (16B aligned)
    int*   keptr  = (int*)(ws + 2759168);                // 19,200
    int*   keptn  = (int*)(ws + 2778368);                // 19,200
    int*   kcarr  = (int*)(ws + 2797568);                // 1,024  (total 2,798,592)

    const int nrows = BATCH * NCAND;                     // 403200
    k_init<<<128, 256, 0, stream>>>(hist, keys, cnt);
    k_score<<<nrows / TILE_ROWS, 256, 0, stream>>>(pred, score, hist);
    k_findT<<<BATCH, 256, 0, stream>>>(hist, Tarr);
    k_gather<<<dim3((NCAND + 255) / 256, BATCH), 256, 0, stream>>>(score, Tarr, keys, cnt);
    k_sort<<<BATCH, 1024, 0, stream>>>(pred, keys, cnt, topidx, topsc, topcls, boxes);
    k_iou<<<(BATCH * KTOP * 16) / 256, 256, 0, stream>>>(boxes, M);
    k_nms<<<BATCH, 1024, 0, stream>>>(M, cnt, topidx, keptr, keptn, kcarr);
    k_out<<<dim3(BATCH, (MAXDET + OSLICE - 1) / OSLICE), 256, 0, stream>>>(
        logits, boxes, topsc, topcls, keptr, keptn, kcarr, out);
}

// Round 8
// 143.228 us; speedup vs baseline: 1.2627x; 1.0795x over previous
//
#include <hip/hip_runtime.h>
#include <hip/hip_bf16.h>

#define BATCH 16
#define NCAND 25200
#define NCLS 80
#define PREDC 85
#define KTOP 1000
#define MAXDET 300
#define CAP 2048
#define NBINS 1024
#define TILE_ROWS 128
#define CONF 0.45f
#define HSCALE ((float)NBINS / (1.0f - 0.45f))
#define CNT_STRIDE 16   // ints; 64B between per-image counters

typedef unsigned long long ull;

// ---------------- K0: zero/init workspace ----------------
__global__ __launch_bounds__(256) void k_init(int* __restrict__ hist,
                                              ull* __restrict__ keys,
                                              int* __restrict__ cnt) {
    int t = blockIdx.x * 256 + threadIdx.x;          // 128 blocks -> 32768 threads
    keys[t] = ~0ULL;                                 // 16*2048 = 32768
    if (t < BATCH * NBINS) hist[t] = 0;              // 16384
    if (t < BATCH * CNT_STRIDE) cnt[t] = 0;
}

// ------- K1: score + argmax class + xyxy box + histogram (single pred pass) -------
__global__ __launch_bounds__(256) void k_score(const float* __restrict__ pred,
                                               float* __restrict__ score,
                                               float* __restrict__ bx,
                                               int* __restrict__ cls,
                                               int* __restrict__ hist) {
    __shared__ float lds[TILE_ROWS * PREDC];   // 43,520 B
    int tile = blockIdx.x;
    int tid = threadIdx.x;
    size_t base = (size_t)tile * (TILE_ROWS * PREDC);
    const float4* src4 = (const float4*)(pred + base);
    float4* l4 = (float4*)lds;
    const int NV4 = TILE_ROWS * PREDC / 4;  // 2720
    for (int k = tid; k < NV4; k += 256) l4[k] = src4[k];
    __syncthreads();
    if (tid < TILE_ROWS) {
        const float* row = lds + tid * PREDC;
        float obj = row[4];
        float best = -1.0f; int bj = 0;
        #pragma unroll 8
        for (int c = 0; c < NCLS; ++c) {
            float v = row[5 + c] * obj;
            if (v > best) { best = v; bj = c; }   // first-max tie-break (jnp.argmax)
        }
        bool valid = (obj > CONF) && (best > CONF);
        float s = valid ? best : -1.0f;
        int grow = tile * TILE_ROWS + tid;
        score[grow] = s;
        cls[grow] = bj;
        float cx = row[0], cy = row[1], w = row[2], h = row[3];
        ((float4*)bx)[grow] = make_float4(cx - w * 0.5f, cy - h * 0.5f,
                                          cx + w * 0.5f, cy + h * 0.5f);
        if (s > CONF) {
            int b = grow / NCAND;
            int bin = (int)((s - CONF) * HSCALE);
            bin = bin < 0 ? 0 : (bin > NBINS - 1 ? NBINS - 1 : bin);
            atomicAdd(&hist[b * NBINS + bin], 1);
        }
    }
}

// ---------------- K2: per-image threshold bin via suffix scan ----------------
__global__ __launch_bounds__(256) void k_findT(const int* __restrict__ hist,
                                               int* __restrict__ Tarr) {
    int b = blockIdx.x, tid = threadIdx.x;
    __shared__ int h[NBINS];
    __shared__ int s_T;
    if (tid == 0) s_T = 0;
    #pragma unroll
    for (int k = 0; k < 4; ++k) h[tid + k * 256] = hist[b * NBINS + tid + k * 256];
    __syncthreads();
    for (int off = 1; off < NBINS; off <<= 1) {
        int tmp[4];
        #pragma unroll
        for (int k = 0; k < 4; ++k) {
            int idx = tid + k * 256;
            tmp[k] = (idx + off < NBINS) ? h[idx + off] : 0;
        }
        __syncthreads();
        #pragma unroll
        for (int k = 0; k < 4; ++k) h[tid + k * 256] += tmp[k];
        __syncthreads();
    }
    #pragma unroll
    for (int k = 0; k < 4; ++k) {
        int idx = tid + k * 256;
        int S = h[idx];
        int Sn = (idx + 1 < NBINS) ? h[idx + 1] : 0;
        if (S >= KTOP && Sn < KTOP) s_T = idx;   // unique (suffix monotone)
    }
    __syncthreads();
    if (tid == 0) Tarr[b] = s_T;
}

// ---------------- K3: gather survivors, one atomic per block ----------------
__global__ __launch_bounds__(256) void k_gather(const float* __restrict__ score,
                                                const int* __restrict__ Tarr,
                                                ull* __restrict__ keys,
                                                int* __restrict__ cnt) {
    int b = blockIdx.y;
    int n = blockIdx.x * 256 + threadIdx.x;
    int tid = threadIdx.x;
    __shared__ int wbase[4];
    __shared__ int sT;
    if (tid == 0) sT = Tarr[b];
    __syncthreads();
    bool want = false;
    float s = 0.0f;
    if (n < NCAND) {
        s = score[b * NCAND + n];
        if (s > CONF) {
            int bin = (int)((s - CONF) * HSCALE);
            bin = bin < 0 ? 0 : (bin > NBINS - 1 ? NBINS - 1 : bin);
            want = (bin >= sT);
        }
    }
    ull m = __ballot(want);
    int lane = tid & 63, widx = tid >> 6;
    if (lane == 0) wbase[widx] = __popcll(m);
    __syncthreads();
    if (tid == 0) {
        int t0 = wbase[0], t1 = wbase[1], t2 = wbase[2], t3 = wbase[3];
        int tot = t0 + t1 + t2 + t3;
        int b0 = tot ? atomicAdd(&cnt[b * CNT_STRIDE], tot) : 0;
        wbase[0] = b0; wbase[1] = b0 + t0; wbase[2] = b0 + t0 + t1; wbase[3] = b0 + t0 + t1 + t2;
    }
    __syncthreads();
    if (want) {
        int pos = wbase[widx] + __popcll(m & ((1ULL << lane) - 1ULL));
        if (pos < CAP) {
            unsigned int sb = __float_as_uint(s);
            keys[b * CAP + pos] = ((ull)(~sb) << 32) | (unsigned)n;
        }
    }
}

// ------ K4: per-image bitonic sort (P=1024 or 2048) + emit top-K (no pred read) ----
__global__ __launch_bounds__(1024) void k_sort(const float* __restrict__ bx,
                                               const int* __restrict__ cls,
                                               const ull* __restrict__ keys,
                                               const int* __restrict__ cnt,
                                               int* __restrict__ topidx,
                                               float* __restrict__ topsc,
                                               int* __restrict__ topcls,
                                               float* __restrict__ boxes) {
    int b = blockIdx.x, tid = threadIdx.x;
    __shared__ ull sbuf[CAP];
    __shared__ int s_C2;
    if (tid == 0) {
        int c = cnt[b * CNT_STRIDE];
        s_C2 = c > CAP ? CAP : c;
    }
    __syncthreads();
    int C2 = s_C2;
    unsigned P = (C2 <= 1024) ? 1024u : 2048u;
    sbuf[tid] = keys[b * CAP + tid];
    if (P > 1024) sbuf[tid + 1024] = keys[b * CAP + tid + 1024];
    __syncthreads();
    for (unsigned k = 2; k <= P; k <<= 1) {
        for (unsigned j = k >> 1; j > 0; j >>= 1) {
            for (unsigned t = tid; t < P; t += 1024) {
                unsigned ixj = t ^ j;
                if (ixj > t) {
                    ull a = sbuf[t], bb = sbuf[ixj];
                    if ((a > bb) == ((t & k) == 0)) { sbuf[t] = bb; sbuf[ixj] = a; }
                }
            }
            __syncthreads();
        }
    }
    if (tid < KTOP) {
        int o = b * KTOP + tid;
        if (tid < C2) {
            ull key = sbuf[tid];
            int n = (int)(key & 0xFFFFFFFFULL);
            float s = __uint_as_float(~(unsigned int)(key >> 32));
            topidx[o] = n;
            topsc[o] = s;
            topcls[o] = cls[b * NCAND + n];
            ((float4*)boxes)[o] = ((const float4*)bx)[b * NCAND + n];
        } else {
            topidx[o] = 0; topsc[o] = -1.0f; topcls[o] = 0;
            ((float4*)boxes)[o] = make_float4(0.f, 0.f, 0.f, 0.f);
        }
    }
}

// ---------------- K5: IoU bitmask (j>i, iou>thr) ----------------
__global__ __launch_bounds__(256) void k_iou(const float* __restrict__ boxes,
                                             ull* __restrict__ M) {
    #pragma clang fp contract(off)
    int g = blockIdx.x * 256 + threadIdx.x;   // 16*1000*16 = 256000
    int w = g & 15;
    int bi = g >> 4;                          // 0..15999
    int i = bi % KTOP;
    int b = bi / KTOP;
    int j0 = w * 64;
    if (j0 + 63 <= i) {                       // whole block strictly j<=i -> zero
        M[(size_t)bi * 16 + w] = 0ULL;
        return;
    }
    const float4* bxp = (const float4*)boxes + (size_t)b * KTOP;
    float4 A = bxp[i];
    float areaA = (A.z - A.x) * (A.w - A.y);
    ull word = 0;
    int jend = j0 + 64; if (jend > KTOP) jend = KTOP;
    #pragma unroll 4
    for (int j = j0; j < jend; ++j) {
        float4 Bb = bxp[j];
        float areaB = (Bb.z - Bb.x) * (Bb.w - Bb.y);
        float lx = fmaxf(A.x, Bb.x), ly = fmaxf(A.y, Bb.y);
        float rx = fminf(A.z, Bb.z), ry = fminf(A.w, Bb.w);
        float ww = rx - lx; ww = ww > 0.f ? ww : 0.f;
        float hh = ry - ly; hh = hh > 0.f ? hh : 0.f;
        float inter = ww * hh;
        float denom = ((areaA + areaB) - inter) + 1e-9f;
        float iou = inter / denom;
        if (j > i && iou > 0.45f) word |= 1ULL << (j - j0);
    }
    M[(size_t)bi * 16 + w] = word;
}

// ------ K6: block-NMS (staged dbuf + wave0 scalar resolve) + top-300 outputs ------
__global__ __launch_bounds__(1024) void k_nms_out(const ull* __restrict__ M,
                                                  const int* __restrict__ cnt,
                                                  const float* __restrict__ logits,
                                                  const int* __restrict__ topidx,
                                                  const float* __restrict__ topsc,
                                                  const int* __restrict__ topcls,
                                                  const float* __restrict__ boxes,
                                                  float* __restrict__ out) {
    __shared__ ull buf[2][64 * 17];   // stride-17 pad: <=4-way bank conflict
    __shared__ ull s_keep[16];
    __shared__ int kept_r[MAXDET];
    __shared__ int kept_n[MAXDET];
    __shared__ int s_kc;
    int b = blockIdx.x, tid = threadIdx.x;
    int kc0 = cnt[b * CNT_STRIDE]; if (kc0 > KTOP) kc0 = KTOP;
    const ull* Mb = M + (size_t)b * KTOP * 16;
    // stage block 0 (all 1024 threads, coalesced)
    buf[0][(tid >> 4) * 17 + (tid & 15)] = Mb[tid];
    __syncthreads();
    ull supp;
    {
        int w = tid & 15, lo = w * 64;
        if (kc0 <= lo) supp = ~0ULL;
        else if (kc0 >= lo + 64) supp = 0ULL;
        else supp = (~0ULL) << (kc0 - lo);
    }
    for (int rb = 0; rb < 16; ++rb) {
        int cur = rb & 1, nxt = cur ^ 1;
        if (tid >= 64) {
            if (rb < 15) {
                // 960 threads stage the next 1024-word block
                for (int u = tid - 64; u < 1024; u += 960) {
                    int idx = (rb + 1) * 1024 + u;
                    int g = idx < 16000 ? idx : 15999;   // tail masked by 'removed'
                    buf[nxt][(u >> 4) * 17 + (u & 15)] = Mb[g];
                }
            }
        } else {
            int l = tid, w = l & 15, q = l >> 4;
            const ull* B = buf[cur];
            ull drow = B[l * 17 + rb];
            ull crow[16];
            #pragma unroll
            for (int k = 0; k < 16; ++k) crow[k] = B[(q + 4 * k) * 17 + w];
            // merged supp word rb -> wave-uniform scalar
            int slo = (int)(supp & 0xffffffffULL);
            int shi = (int)(supp >> 32);
            unsigned rlo = (unsigned)__builtin_amdgcn_readlane(slo, rb)
                         | (unsigned)__builtin_amdgcn_readlane(slo, rb + 16)
                         | (unsigned)__builtin_amdgcn_readlane(slo, rb + 32)
                         | (unsigned)__builtin_amdgcn_readlane(slo, rb + 48);
            unsigned rhi = (unsigned)__builtin_amdgcn_readlane(shi, rb)
                         | (unsigned)__builtin_amdgcn_readlane(shi, rb + 16)
                         | (unsigned)__builtin_amdgcn_readlane(shi, rb + 32)
                         | (unsigned)__builtin_amdgcn_readlane(shi, rb + 48);
            ull removed = ((ull)rhi << 32) | rlo;
            int dlo_v = (int)(drow & 0xffffffffULL);
            int dhi_v = (int)(drow >> 32);
            // 64-step serial resolve on wave-uniform scalars (SALU chain)
            #pragma unroll
            for (int s = 0; s < 64; ++s) {
                unsigned dl = (unsigned)__builtin_amdgcn_readlane(dlo_v, s);
                unsigned dh = (unsigned)__builtin_amdgcn_readlane(dhi_v, s);
                ull d64 = ((ull)dh << 32) | dl;
                if (!((removed >> s) & 1ULL)) removed |= d64;
            }
            // dense parallel apply
            ull acc = 0;
            #pragma unroll
            for (int k = 0; k < 16; ++k) {
                int r = q + 4 * k;
                if (!((removed >> r) & 1ULL)) acc |= crow[k];
            }
            supp |= acc;
        }
        __syncthreads();
    }
    if (tid < 64) {
        supp |= __shfl_xor(supp, 16);
        supp |= __shfl_xor(supp, 32);
        if (tid < 16) s_keep[tid] = ~supp;
    }
    __syncthreads();
    if (tid < 16) {
        int pre = 0;
        for (int u = 0; u < tid; ++u) pre += __popcll(s_keep[u]);
        ull wv = s_keep[tid];
        int rank = pre;
        while (wv) {
            int bit = __builtin_ctzll(wv);
            if (rank < MAXDET) kept_r[rank] = tid * 64 + bit;
            rank++;
            wv &= wv - 1;
        }
        if (tid == 15) s_kc = rank < MAXDET ? rank : MAXDET;
    }
    __syncthreads();
    int kc = s_kc;
    if (tid < MAXDET && tid < kc) kept_n[tid] = topidx[b * KTOP + kept_r[tid]];
    __syncthreads();
    // ---- output phase (all 1024 threads) ----
    float* det = out;                                        // [16][300][6]
    float* mask_o = out + BATCH * MAXDET * 6;                // [16][300]
    float* lgo = out + BATCH * MAXDET * 6 + BATCH * MAXDET;  // [16][300][80]
    for (int idx = tid; idx < MAXDET * 6; idx += 1024) {
        int s = idx / 6, col = idx % 6;
        float v = 0.f;
        if (s < kc) {
            int o = b * KTOP + kept_r[s];
            if (col < 4) v = boxes[o * 4 + col];
            else if (col == 4) v = topsc[o];
            else v = (float)topcls[o];
        }
        det[b * MAXDET * 6 + idx] = v;
    }
    for (int s = tid; s < MAXDET; s += 1024)
        mask_o[b * MAXDET + s] = (s < kc) ? 1.0f : 0.0f;
    // logits rows are 80 floats = 20 float4 (16B-aligned)
    float4* lgo4 = (float4*)(lgo + (size_t)b * MAXDET * NCLS);
    const float4* lg4 = (const float4*)logits;
    for (int idx = tid; idx < MAXDET * (NCLS / 4); idx += 1024) {
        int s = idx / (NCLS / 4), cc = idx % (NCLS / 4);
        float4 v = make_float4(0.f, 0.f, 0.f, 0.f);
        if (s < kc) v = lg4[((size_t)b * NCAND + kept_n[s]) * (NCLS / 4) + cc];
        lgo4[idx] = v;
    }
}

extern "C" void kernel_launch(void* const* d_in, const int* in_sizes, int n_in,
                              void* d_out, int out_size, void* d_ws, size_t ws_size,
                              hipStream_t stream) {
    (void)in_sizes; (void)n_in; (void)out_size; (void)ws_size;
    const float* pred = (const float*)d_in[0];
    const float* logits = (const float*)d_in[1];
    float* out = (float*)d_out;
    char* ws = (char*)d_ws;

    // workspace layout (bytes). Region A [0, 2,048,000) is time-shared:
    //   score/hist/Tarr live K0..K3; M overlays them, live K5..K6.
    float* score  = (float*)(ws + 0);                    // 1,612,800
    int*   hist   = (int*)(ws + 1612800);                // 65,536
    int*   Tarr   = (int*)(ws + 1678336);                // 64
    ull*   M      = (ull*)(ws + 0);                      // 2,048,000 (overlay)
    ull*   keys   = (ull*)(ws + 2048000);                // 262,144
    int*   cnt    = (int*)(ws + 2310144);                // 1,024 (16 imgs x 64B)
    int*   topidx = (int*)(ws + 2311168);                // 64,000
    float* topsc  = (float*)(ws + 2375168);              // 64,000
    int*   topcls = (int*)(ws + 2439168);                // 64,000
    float* boxes  = (float*)(ws + 2503168);              // 256,000 (16B aligned)
    float* bx     = (float*)(ws + 2759168);              // 6,451,200 (16B aligned)
    int*   cls    = (int*)(ws + 9210368);                // 1,612,800 (total 10,823,168)

    const int nrows = BATCH * NCAND;                     // 403200
    k_init<<<128, 256, 0, stream>>>(hist, keys, cnt);
    k_score<<<nrows / TILE_ROWS, 256, 0, stream>>>(pred, score, bx, cls, hist);
    k_findT<<<BATCH, 256, 0, stream>>>(hist, Tarr);
    k_gather<<<dim3((NCAND + 255) / 256, BATCH), 256, 0, stream>>>(score, Tarr, keys, cnt);
    k_sort<<<BATCH, 1024, 0, stream>>>(bx, cls, keys, cnt, topidx, topsc, topcls, boxes);
    k_iou<<<(BATCH * KTOP * 16) / 256, 256, 0, stream>>>(boxes, M);
    k_nms_out<<<BATCH, 1024, 0, stream>>>(M, cnt, logits, topidx, topsc, topcls, boxes, out);
}

// Round 9
// 131.220 us; speedup vs baseline: 1.3783x; 1.0915x over previous
//
#include <hip/hip_runtime.h>
#include <hip/hip_bf16.h>

#define BATCH 16
#define NCAND 25200
#define NCLS 80
#define PREDC 85
#define KTOP 1000
#define MAXDET 300
#define CAP 2048
#define NBINS 1024
#define TILE_ROWS 128
#define CONF 0.45f
#define HSCALE ((float)NBINS / (1.0f - 0.45f))
#define CNT_STRIDE 16   // ints; 64B between per-image counters

typedef unsigned long long ull;

// ------- K1: score + argmax class + xyxy box (single pred pass, no atomics) -------
__global__ __launch_bounds__(256) void k_score(const float* __restrict__ pred,
                                               float* __restrict__ score,
                                               float* __restrict__ bx,
                                               int* __restrict__ cls) {
    __shared__ float lds[TILE_ROWS * PREDC];   // 43,520 B
    int tile = blockIdx.x;
    int tid = threadIdx.x;
    size_t base = (size_t)tile * (TILE_ROWS * PREDC);
    const float4* src4 = (const float4*)(pred + base);
    float4* l4 = (float4*)lds;
    const int NV4 = TILE_ROWS * PREDC / 4;  // 2720
    for (int k = tid; k < NV4; k += 256) l4[k] = src4[k];
    __syncthreads();
    if (tid < TILE_ROWS) {
        const float* row = lds + tid * PREDC;
        float obj = row[4];
        float best = -1.0f; int bj = 0;
        #pragma unroll 8
        for (int c = 0; c < NCLS; ++c) {
            float v = row[5 + c] * obj;
            if (v > best) { best = v; bj = c; }   // first-max tie-break (jnp.argmax)
        }
        bool valid = (obj > CONF) && (best > CONF);
        float s = valid ? best : -1.0f;
        int grow = tile * TILE_ROWS + tid;
        score[grow] = s;
        cls[grow] = bj;
        float cx = row[0], cy = row[1], w = row[2], h = row[3];
        ((float4*)bx)[grow] = make_float4(cx - w * 0.5f, cy - h * 0.5f,
                                          cx + w * 0.5f, cy + h * 0.5f);
    }
}

// ---- K2: per-image hist+T+gather+hybrid-bitonic-sort+emit (one 1024-thr block) ----
__device__ __forceinline__ void cmpx(ull& r, ull p, bool keepMin) {
    ull mn = r < p ? r : p;
    ull mx = r < p ? p : r;
    r = keepMin ? mn : mx;
}

__global__ __launch_bounds__(1024) void k_topk(const float* __restrict__ score,
                                               const float* __restrict__ bx,
                                               const int* __restrict__ cls,
                                               int* __restrict__ topidx,
                                               float* __restrict__ topsc,
                                               int* __restrict__ topcls,
                                               float* __restrict__ boxes,
                                               int* __restrict__ cnt) {
    __shared__ int hist[NBINS];        // 4 KB
    __shared__ ull sbuf[CAP];          // 16 KB
    __shared__ int s_T, s_base;
    int b = blockIdx.x, tid = threadIdx.x;
    int lane = tid & 63;
    const float* sc = score + (size_t)b * NCAND;
    const float4* sc4 = (const float4*)sc;
    const int NF4 = NCAND / 4;         // 6300
    hist[tid] = 0;
    if (tid == 0) { s_T = 0; s_base = 0; }
    __syncthreads();
    // pass 1: histogram (float4)
    for (int f = tid; f < NF4; f += 1024) {
        float4 v4 = sc4[f];
        float vs[4] = {v4.x, v4.y, v4.z, v4.w};
        #pragma unroll
        for (int e = 0; e < 4; ++e) {
            float s = vs[e];
            if (s > CONF) {
                int bin = (int)((s - CONF) * HSCALE);
                bin = bin < 0 ? 0 : (bin > NBINS - 1 ? NBINS - 1 : bin);
                atomicAdd(&hist[bin], 1);
            }
        }
    }
    __syncthreads();
    // suffix scan (Hillis-Steele, 1 bin/thread)
    for (int off = 1; off < NBINS; off <<= 1) {
        int v = (tid + off < NBINS) ? hist[tid + off] : 0;
        __syncthreads();
        hist[tid] += v;
        __syncthreads();
    }
    {
        int S = hist[tid];
        int Sn = (tid + 1 < NBINS) ? hist[tid + 1] : 0;
        if (S >= KTOP && Sn < KTOP) s_T = tid;   // unique (suffix monotone)
    }
    sbuf[tid] = ~0ULL;
    sbuf[tid + 1024] = ~0ULL;
    __syncthreads();
    int T = s_T;
    // pass 2: gather survivors into LDS (wave-compaction, LDS-atomic base)
    for (int f = tid; f < NF4; f += 1024) {
        float4 v4 = sc4[f];
        float vs[4] = {v4.x, v4.y, v4.z, v4.w};
        #pragma unroll
        for (int e = 0; e < 4; ++e) {
            float s = vs[e];
            bool want = false;
            if (s > CONF) {
                int bin = (int)((s - CONF) * HSCALE);
                bin = bin < 0 ? 0 : (bin > NBINS - 1 ? NBINS - 1 : bin);
                want = (bin >= T);
            }
            ull m = __ballot(want);
            int wb = 0;
            if (lane == 0 && m) wb = atomicAdd(&s_base, (int)__popcll(m));
            wb = __shfl(wb, 0);
            if (want) {
                int pos = wb + (int)__popcll(m & ((1ULL << lane) - 1ULL));
                if (pos < CAP) {
                    unsigned sb2 = __float_as_uint(s);
                    sbuf[pos] = ((ull)(~sb2) << 32) | (unsigned)(f * 4 + e);
                }
            }
        }
    }
    __syncthreads();
    int C2 = s_base; if (C2 > CAP) C2 = CAP;
    // hybrid bitonic sort of 2048 keys: regs r0,r1; shfl for j<=32, LDS for j>=64
    ull r0 = sbuf[tid];
    ull r1 = sbuf[tid + 1024];
    int t2 = tid + 1024;
    // k = 2..64: pure in-wave
    #pragma unroll
    for (unsigned k = 2; k <= 64; k <<= 1) {
        #pragma unroll
        for (unsigned j = k >> 1; j > 0; j >>= 1) {
            ull p0 = __shfl_xor(r0, (int)j);
            ull p1 = __shfl_xor(r1, (int)j);
            bool amLow = ((tid & j) == 0);
            cmpx(r0, p0, amLow == ((tid & k) == 0));
            cmpx(r1, p1, amLow == ((t2 & k) == 0));
        }
    }
    // k = 128..1024: LDS for j>=64, shfl for j<=32
    #pragma unroll
    for (unsigned k = 128; k <= 1024; k <<= 1) {
        #pragma unroll
        for (unsigned j = k >> 1; j >= 64; j >>= 1) {
            sbuf[tid] = r0; sbuf[t2] = r1;
            __syncthreads();
            ull p0 = sbuf[tid ^ j];
            ull p1 = sbuf[t2 ^ j];
            cmpx(r0, p0, ((tid & j) == 0) == ((tid & k) == 0));
            cmpx(r1, p1, ((t2 & j) == 0) == ((t2 & k) == 0));
            __syncthreads();
        }
        #pragma unroll
        for (unsigned j = 32; j > 0; j >>= 1) {
            ull p0 = __shfl_xor(r0, (int)j);
            ull p1 = __shfl_xor(r1, (int)j);
            bool amLow = ((tid & j) == 0);
            cmpx(r0, p0, amLow == ((tid & k) == 0));
            cmpx(r1, p1, amLow == ((t2 & k) == 0));
        }
    }
    // k = 2048 (final ascending merge)
    {
        if (r1 < r0) { ull t = r0; r0 = r1; r1 = t; }   // j=1024, in-thread
        #pragma unroll
        for (unsigned j = 512; j >= 64; j >>= 1) {
            sbuf[tid] = r0; sbuf[t2] = r1;
            __syncthreads();
            ull p0 = sbuf[tid ^ j];
            ull p1 = sbuf[t2 ^ j];
            cmpx(r0, p0, ((tid & j) == 0));
            cmpx(r1, p1, ((t2 & j) == 0));
            __syncthreads();
        }
        #pragma unroll
        for (unsigned j = 32; j > 0; j >>= 1) {
            ull p0 = __shfl_xor(r0, (int)j);
            ull p1 = __shfl_xor(r1, (int)j);
            bool amLow = ((tid & j) == 0);
            cmpx(r0, p0, amLow);
            cmpx(r1, p1, amLow);
        }
    }
    // emit top-K from r0 (ranks 0..1023)
    if (tid < KTOP) {
        int o = b * KTOP + tid;
        if (tid < C2) {
            int n = (int)(r0 & 0xFFFFFFFFULL);
            float s = __uint_as_float(~(unsigned)(r0 >> 32));
            topidx[o] = n;
            topsc[o] = s;
            topcls[o] = cls[b * NCAND + n];
            ((float4*)boxes)[o] = ((const float4*)bx)[b * NCAND + n];
        } else {
            topidx[o] = 0; topsc[o] = -1.0f; topcls[o] = 0;
            ((float4*)boxes)[o] = make_float4(0.f, 0.f, 0.f, 0.f);
        }
    }
    if (tid == 0) cnt[b * CNT_STRIDE] = C2;
}

// ---------------- K3: IoU bitmask (j>i, iou>thr) ----------------
__global__ __launch_bounds__(256) void k_iou(const float* __restrict__ boxes,
                                             ull* __restrict__ M) {
    #pragma clang fp contract(off)
    int g = blockIdx.x * 256 + threadIdx.x;   // 16*1000*16 = 256000
    int w = g & 15;
    int bi = g >> 4;                          // 0..15999
    int i = bi % KTOP;
    int b = bi / KTOP;
    int j0 = w * 64;
    if (j0 + 63 <= i) {                       // whole block strictly j<=i -> zero
        M[(size_t)bi * 16 + w] = 0ULL;
        return;
    }
    const float4* bxp = (const float4*)boxes + (size_t)b * KTOP;
    float4 A = bxp[i];
    float areaA = (A.z - A.x) * (A.w - A.y);
    ull word = 0;
    int jend = j0 + 64; if (jend > KTOP) jend = KTOP;
    #pragma unroll 4
    for (int j = j0; j < jend; ++j) {
        float4 Bb = bxp[j];
        float areaB = (Bb.z - Bb.x) * (Bb.w - Bb.y);
        float lx = fmaxf(A.x, Bb.x), ly = fmaxf(A.y, Bb.y);
        float rx = fminf(A.z, Bb.z), ry = fminf(A.w, Bb.w);
        float ww = rx - lx; ww = ww > 0.f ? ww : 0.f;
        float hh = ry - ly; hh = hh > 0.f ? hh : 0.f;
        float inter = ww * hh;
        float denom = ((areaA + areaB) - inter) + 1e-9f;
        float iou = inter / denom;
        if (j > i && iou > 0.45f) word |= 1ULL << (j - j0);
    }
    M[(size_t)bi * 16 + w] = word;
}

// ------ K4: block-NMS (staged dbuf + wave0 scalar resolve) + top-300 outputs ------
__global__ __launch_bounds__(1024) void k_nms_out(const ull* __restrict__ M,
                                                  const int* __restrict__ cnt,
                                                  const float* __restrict__ logits,
                                                  const int* __restrict__ topidx,
                                                  const float* __restrict__ topsc,
                                                  const int* __restrict__ topcls,
                                                  const float* __restrict__ boxes,
                                                  float* __restrict__ out) {
    __shared__ ull buf[2][64 * 17];   // stride-17 pad: <=4-way bank conflict
    __shared__ ull s_keep[16];
    __shared__ int kept_r[MAXDET];
    __shared__ int kept_n[MAXDET];
    __shared__ int s_kc;
    int b = blockIdx.x, tid = threadIdx.x;
    int kc0 = cnt[b * CNT_STRIDE]; if (kc0 > KTOP) kc0 = KTOP;
    const ull* Mb = M + (size_t)b * KTOP * 16;
    // stage block 0 (all 1024 threads, coalesced)
    buf[0][(tid >> 4) * 17 + (tid & 15)] = Mb[tid];
    __syncthreads();
    ull supp;
    {
        int w = tid & 15, lo = w * 64;
        if (kc0 <= lo) supp = ~0ULL;
        else if (kc0 >= lo + 64) supp = 0ULL;
        else supp = (~0ULL) << (kc0 - lo);
    }
    for (int rb = 0; rb < 16; ++rb) {
        int cur = rb & 1, nxt = cur ^ 1;
        if (tid >= 64) {
            if (rb < 15) {
                // 960 threads stage the next 1024-word block
                for (int u = tid - 64; u < 1024; u += 960) {
                    int idx = (rb + 1) * 1024 + u;
                    int g = idx < 16000 ? idx : 15999;   // tail masked by 'removed'
                    buf[nxt][(u >> 4) * 17 + (u & 15)] = Mb[g];
                }
            }
        } else {
            int l = tid, w = l & 15, q = l >> 4;
            const ull* B = buf[cur];
            ull drow = B[l * 17 + rb];
            ull crow[16];
            #pragma unroll
            for (int k = 0; k < 16; ++k) crow[k] = B[(q + 4 * k) * 17 + w];
            // merged supp word rb -> wave-uniform scalar
            int slo = (int)(supp & 0xffffffffULL);
            int shi = (int)(supp >> 32);
            unsigned rlo = (unsigned)__builtin_amdgcn_readlane(slo, rb)
                         | (unsigned)__builtin_amdgcn_readlane(slo, rb + 16)
                         | (unsigned)__builtin_amdgcn_readlane(slo, rb + 32)
                         | (unsigned)__builtin_amdgcn_readlane(slo, rb + 48);
            unsigned rhi = (unsigned)__builtin_amdgcn_readlane(shi, rb)
                         | (unsigned)__builtin_amdgcn_readlane(shi, rb + 16)
                         | (unsigned)__builtin_amdgcn_readlane(shi, rb + 32)
                         | (unsigned)__builtin_amdgcn_readlane(shi, rb + 48);
            ull removed = ((ull)rhi << 32) | rlo;
            int dlo_v = (int)(drow & 0xffffffffULL);
            int dhi_v = (int)(drow >> 32);
            // 64-step serial resolve on wave-uniform scalars (SALU chain)
            #pragma unroll
            for (int s = 0; s < 64; ++s) {
                unsigned dl = (unsigned)__builtin_amdgcn_readlane(dlo_v, s);
                unsigned dh = (unsigned)__builtin_amdgcn_readlane(dhi_v, s);
                ull d64 = ((ull)dh << 32) | dl;
                if (!((removed >> s) & 1ULL)) removed |= d64;
            }
            // dense parallel apply
            ull acc = 0;
            #pragma unroll
            for (int k = 0; k < 16; ++k) {
                int r = q + 4 * k;
                if (!((removed >> r) & 1ULL)) acc |= crow[k];
            }
            supp |= acc;
        }
        __syncthreads();
    }
    if (tid < 64) {
        supp |= __shfl_xor(supp, 16);
        supp |= __shfl_xor(supp, 32);
        if (tid < 16) s_keep[tid] = ~supp;
    }
    __syncthreads();
    if (tid < 16) {
        int pre = 0;
        for (int u = 0; u < tid; ++u) pre += __popcll(s_keep[u]);
        ull wv = s_keep[tid];
        int rank = pre;
        while (wv) {
            int bit = __builtin_ctzll(wv);
            if (rank < MAXDET) kept_r[rank] = tid * 64 + bit;
            rank++;
            wv &= wv - 1;
        }
        if (tid == 15) s_kc = rank < MAXDET ? rank : MAXDET;
    }
    __syncthreads();
    int kc = s_kc;
    if (tid < MAXDET && tid < kc) kept_n[tid] = topidx[b * KTOP + kept_r[tid]];
    __syncthreads();
    // ---- output phase (all 1024 threads) ----
    float* det = out;                                        // [16][300][6]
    float* mask_o = out + BATCH * MAXDET * 6;                // [16][300]
    float* lgo = out + BATCH * MAXDET * 6 + BATCH * MAXDET;  // [16][300][80]
    for (int idx = tid; idx < MAXDET * 6; idx += 1024) {
        int s = idx / 6, col = idx % 6;
        float v = 0.f;
        if (s < kc) {
            int o = b * KTOP + kept_r[s];
            if (col < 4) v = boxes[o * 4 + col];
            else if (col == 4) v = topsc[o];
            else v = (float)topcls[o];
        }
        det[b * MAXDET * 6 + idx] = v;
    }
    for (int s = tid; s < MAXDET; s += 1024)
        mask_o[b * MAXDET + s] = (s < kc) ? 1.0f : 0.0f;
    // logits rows are 80 floats = 20 float4 (16B-aligned)
    float4* lgo4 = (float4*)(lgo + (size_t)b * MAXDET * NCLS);
    const float4* lg4 = (const float4*)logits;
    for (int idx = tid; idx < MAXDET * (NCLS / 4); idx += 1024) {
        int s = idx / (NCLS / 4), cc = idx % (NCLS / 4);
        float4 v = make_float4(0.f, 0.f, 0.f, 0.f);
        if (s < kc) v = lg4[((size_t)b * NCAND + kept_n[s]) * (NCLS / 4) + cc];
        lgo4[idx] = v;
    }
}

extern "C" void kernel_launch(void* const* d_in, const int* in_sizes, int n_in,
                              void* d_out, int out_size, void* d_ws, size_t ws_size,
                              hipStream_t stream) {
    (void)in_sizes; (void)n_in; (void)out_size; (void)ws_size;
    const float* pred = (const float*)d_in[0];
    const float* logits = (const float*)d_in[1];
    float* out = (float*)d_out;
    char* ws = (char*)d_ws;

    // workspace layout (bytes). score+bx dead after k_topk; M overlays them.
    float* score  = (float*)(ws + 0);                    // 1,612,800
    float* bx     = (float*)(ws + 1612800);              // 6,451,200 (16B aligned)
    int*   cls    = (int*)(ws + 8064000);                // 1,612,800
    ull*   M      = (ull*)(ws + 0);                      // 2,048,000 (overlay on score+bx head)
    int*   cnt    = (int*)(ws + 9676800);                // 1,024 (16 imgs x 64B)
    int*   topidx = (int*)(ws + 9677824);                // 64,000
    float* topsc  = (float*)(ws + 9741824);              // 64,000
    int*   topcls = (int*)(ws + 9805824);                // 64,000
    float* boxes  = (float*)(ws + 9869824);              // 256,000 (16B aligned)
                                                         // total 10,125,824

    const int nrows = BATCH * NCAND;                     // 403200
    k_score<<<nrows / TILE_ROWS, 256, 0, stream>>>(pred, score, bx, cls);
    k_topk<<<BATCH, 1024, 0, stream>>>(score, bx, cls, topidx, topsc, topcls, boxes, cnt);
    k_iou<<<(BATCH * KTOP * 16) / 256, 256, 0, stream>>>(boxes, M);
    k_nms_out<<<BATCH, 1024, 0, stream>>>(M, cnt, logits, topidx, topsc, topcls, boxes, out);
}